// Round 1
// baseline (326.771 us; speedup 1.0000x reference)
//
#include <hip/hip_runtime.h>
#include <math.h>

// Problem constants (from reference setup_inputs)
#define NB     64      // batch
#define N1V    8192    // obj points per batch
#define NV     778     // recon / gt verts
#define NFACE  1538
#define NZ     64
#define NPAR   61
#define NPRIOR 204
#define PPT    4       // obj points per thread in main kernel
#define CPB    8       // chunks per batch: 8192 / (256*4)

__device__ __constant__ int c_prior[NPRIOR] = {
  697,698,699,700,712,713,714,715,737,738,739,740,741,743,744,745,746,748,749,750,
  753,754,755,756,757,758,759,760,761,762,763,764,765,766,767,768,
  46,47,48,49,164,165,166,167,194,195,223,237,238,280,281,298,301,317,320,323,
  324,325,326,327,328,329,330,331,332,333,340,341,342,343,344,345,346,347,348,349,
  350,351,352,353,354,355,
  356,357,358,359,375,376,386,387,396,397,402,403,413,429,433,434,435,436,437,438,
  439,440,441,442,443,444,452,453,454,455,456,459,460,461,462,463,464,465,466,467,
  468,469,470,471,484,485,486,496,497,506,507,513,514,524,545,546,547,548,549,550,
  551,552,553,555,563,564,565,566,567,570,572,573,574,575,576,577,578,
  580,581,582,583,600,601,602,614,615,624,625,630,631,641,663,664,665,666,667,668,
  670,672,680,681,682,683,684,686,687,688,689,690,691,692,693,694,695,
  73,96,98,99,772,774,775,777
};

// Accumulator layout in d_ws (floats):
// 0: S_param  1: S_kld  2: S_recon(chamfer both dirs)  3: S_cmap  4: N_cmap
// 5: N_gt  6: N_consist  7: S_pen

// ---------------- Kernel 1: small reductions + accumulator init ----------------
__global__ __launch_bounds__(256) void k_small(const float* __restrict__ mean,
                                               const float* __restrict__ log_var,
                                               const float* __restrict__ rp,
                                               const float* __restrict__ xp,
                                               float* __restrict__ acc) {
    int tid = threadIdx.x;
    __shared__ float red[2];
    if (tid < 2) red[tid] = 0.0f;
    __syncthreads();
    float s_param = 0.0f, s_kld = 0.0f;
    for (int i = tid; i < NB * NPAR; i += 256) {
        float d = rp[i] - xp[i];
        s_param += d * d;
    }
    for (int i = tid; i < NB * NZ; i += 256) {
        float m = mean[i], lv = log_var[i];
        s_kld += 1.0f + lv - m * m - expf(lv);
    }
    atomicAdd(&red[0], s_param);
    atomicAdd(&red[1], s_kld);
    __syncthreads();
    if (tid < 2) acc[tid] = red[tid];
    if (tid >= 2 && tid < 8) acc[tid] = 0.0f;   // zero the running accumulators
}

// ---------------- Kernel 2: chamfer(recon, gt) both directions ----------------
__global__ __launch_bounds__(256) void k_chamfer(const float* __restrict__ recon,
                                                 const float* __restrict__ gt,
                                                 float* __restrict__ acc) {
    int b = blockIdx.x >> 2;
    int chunk = blockIdx.x & 3;
    int tid = threadIdx.x;
    __shared__ float4 s_rec[NV];
    __shared__ float4 s_gt[NV];
    __shared__ float red;
    if (tid == 0) red = 0.0f;
    const float* rb = recon + (size_t)b * NV * 3;
    const float* gb = gt    + (size_t)b * NV * 3;
    for (int j = tid; j < NV; j += 256) {
        float x = rb[3*j], y = rb[3*j+1], z = rb[3*j+2];
        s_rec[j] = make_float4(x, y, z, x*x + y*y + z*z);
        x = gb[3*j]; y = gb[3*j+1]; z = gb[3*j+2];
        s_gt[j] = make_float4(x, y, z, x*x + y*y + z*z);
    }
    __syncthreads();
    // 2*NV source points split over 4 chunks
    const int total = 2 * NV;          // 1556
    const int per   = (total + 3) / 4; // 389
    int start = chunk * per;
    int end   = min(start + per, total);
    float local = 0.0f;
    for (int p = start + tid; p < end; p += 256) {
        bool first = (p < NV);
        float4 a = first ? s_rec[p] : s_gt[p - NV];
        const float4* tgt = first ? s_gt : s_rec;
        float nax = -2.0f * a.x, nay = -2.0f * a.y, naz = -2.0f * a.z;
        float m = 3.4e38f;
        for (int j = 0; j < NV; ++j) {
            float4 t = tgt[j];
            float d = fmaf(nax, t.x, fmaf(nay, t.y, fmaf(naz, t.z, t.w)));
            m = fminf(m, d);
        }
        float aw = a.x*a.x + a.y*a.y + a.z*a.z;
        local += fmaxf(aw + m, 0.0f);
    }
    atomicAdd(&red, local);
    __syncthreads();
    if (tid == 0) atomicAdd(&acc[2], red);
}

// ---------------- Kernel 3: main per-obj-point KNNs + flags ----------------
__global__ __launch_bounds__(256) void k_main(const float* __restrict__ obj,
                                              const float* __restrict__ recon,
                                              const float* __restrict__ gt,
                                              const int* __restrict__ faces,
                                              float* __restrict__ acc) {
    int b = blockIdx.x >> 3;     // batch
    int chunk = blockIdx.x & 7;  // 1024-point chunk
    int tid = threadIdx.x;

    __shared__ float4 s_gt[NV];
    __shared__ float4 s_rec[NV];
    __shared__ float4 s_pri[NPRIOR];
    __shared__ float s_vnx[NV], s_vny[NV], s_vnz[NV];
    __shared__ float s_red[5];

    const float* rb = recon + (size_t)b * NV * 3;
    const float* gb = gt    + (size_t)b * NV * 3;
    for (int j = tid; j < NV; j += 256) {
        float x = rb[3*j], y = rb[3*j+1], z = rb[3*j+2];
        s_rec[j] = make_float4(x, y, z, x*x + y*y + z*z);
        x = gb[3*j]; y = gb[3*j+1]; z = gb[3*j+2];
        s_gt[j] = make_float4(x, y, z, x*x + y*y + z*z);
        s_vnx[j] = 0.0f; s_vny[j] = 0.0f; s_vnz[j] = 0.0f;
    }
    if (tid < 5) s_red[tid] = 0.0f;
    __syncthreads();

    // face normals accumulated into vertex normals (LDS atomics)
    for (int f = tid; f < NFACE; f += 256) {
        int i0 = faces[3*f], i1 = faces[3*f+1], i2 = faces[3*f+2];
        float4 p0 = s_rec[i0], p1 = s_rec[i1], p2 = s_rec[i2];
        float e1x = p1.x - p0.x, e1y = p1.y - p0.y, e1z = p1.z - p0.z;
        float e2x = p2.x - p0.x, e2y = p2.y - p0.y, e2z = p2.z - p0.z;
        float fx = e1y * e2z - e1z * e2y;
        float fy = e1z * e2x - e1x * e2z;
        float fz = e1x * e2y - e1y * e2x;
        atomicAdd(&s_vnx[i0], fx); atomicAdd(&s_vny[i0], fy); atomicAdd(&s_vnz[i0], fz);
        atomicAdd(&s_vnx[i1], fx); atomicAdd(&s_vny[i1], fy); atomicAdd(&s_vnz[i1], fz);
        atomicAdd(&s_vnx[i2], fx); atomicAdd(&s_vny[i2], fy); atomicAdd(&s_vnz[i2], fz);
    }
    __syncthreads();
    // normalize normals; build prior subset
    for (int j = tid; j < NV; j += 256) {
        float x = s_vnx[j], y = s_vny[j], z = s_vnz[j];
        float inv = 1.0f / (sqrtf(x*x + y*y + z*z) + 1e-12f);
        s_vnx[j] = x * inv; s_vny[j] = y * inv; s_vnz[j] = z * inv;
    }
    for (int k = tid; k < NPRIOR; k += 256) s_pri[k] = s_rec[c_prior[k]];
    __syncthreads();

    // each thread: PPT consecutive obj points
    const float* ob = obj + ((size_t)b * N1V + (size_t)chunk * 1024) * 3;
    const float4* ob4 = (const float4*)(ob + (size_t)tid * PPT * 3);
    float4 q0 = ob4[0], q1 = ob4[1], q2 = ob4[2];
    float ax[PPT], ay[PPT], az[PPT];
    ax[0]=q0.x; ay[0]=q0.y; az[0]=q0.z;
    ax[1]=q0.w; ay[1]=q1.x; az[1]=q1.y;
    ax[2]=q1.z; ay[2]=q1.w; az[2]=q2.x;
    ax[3]=q2.y; ay[3]=q2.z; az[3]=q2.w;

    float nax[PPT], nay[PPT], naz[PPT], a2[PPT];
    float mgt[PPT], mrec[PPT], mpri[PPT];
    int irec[PPT];
#pragma unroll
    for (int i = 0; i < PPT; ++i) {
        nax[i] = -2.0f * ax[i]; nay[i] = -2.0f * ay[i]; naz[i] = -2.0f * az[i];
        a2[i] = ax[i]*ax[i] + ay[i]*ay[i] + az[i]*az[i];
        mgt[i] = 3.4e38f; mrec[i] = 3.4e38f; mpri[i] = 3.4e38f; irec[i] = 0;
    }

    for (int j = 0; j < NV; ++j) {
        float4 t = s_gt[j];
#pragma unroll
        for (int i = 0; i < PPT; ++i) {
            float d = fmaf(nax[i], t.x, fmaf(nay[i], t.y, fmaf(naz[i], t.z, t.w)));
            mgt[i] = fminf(mgt[i], d);
        }
    }
    for (int j = 0; j < NV; ++j) {
        float4 t = s_rec[j];
#pragma unroll
        for (int i = 0; i < PPT; ++i) {
            float d = fmaf(nax[i], t.x, fmaf(nay[i], t.y, fmaf(naz[i], t.z, t.w)));
            if (d < mrec[i]) { mrec[i] = d; irec[i] = j; }   // first-min like jnp.argmin
        }
    }
    for (int j = 0; j < NPRIOR; ++j) {
        float4 t = s_pri[j];
#pragma unroll
        for (int i = 0; i < PPT; ++i) {
            float d = fmaf(nax[i], t.x, fmaf(nay[i], t.y, fmaf(naz[i], t.z, t.w)));
            mpri[i] = fminf(mpri[i], d);
        }
    }

    float lS_cmap = 0.0f, lN_cmap = 0.0f, lN_gt = 0.0f, lN_cons = 0.0f, lS_pen = 0.0f;
#pragma unroll
    for (int i = 0; i < PPT; ++i) {
        float dgt  = fmaxf(a2[i] + mgt[i],  0.0f);
        float drec = fmaxf(a2[i] + mrec[i], 0.0f);
        float dpri = fmaxf(a2[i] + mpri[i], 0.0f);
        bool cm = drec < 1e-4f;                 // d_rec < 0.01^2
        bool rc = sqrtf(drec) < 0.005f;         // recon_cmap
        bool gc = sqrtf(dgt)  < 0.005f;         // gt_cmap
        if (cm) { lS_cmap += dpri; lN_cmap += 1.0f; }
        if (gc) { lN_gt += 1.0f; if (rc) lN_cons += 1.0f; }
        int j = irec[i];
        float4 nn = s_rec[j];
        float dot = (nn.x - ax[i]) * s_vnx[j]
                  + (nn.y - ay[i]) * s_vny[j]
                  + (nn.z - az[i]) * s_vnz[j];
        if (dot > 0.0f) lS_pen += drec;
    }
    atomicAdd(&s_red[0], lS_cmap);
    atomicAdd(&s_red[1], lN_cmap);
    atomicAdd(&s_red[2], lN_gt);
    atomicAdd(&s_red[3], lN_cons);
    atomicAdd(&s_red[4], lS_pen);
    __syncthreads();
    if (tid < 5) atomicAdd(&acc[3 + tid], s_red[tid]);
}

// ---------------- Kernel 4: finalize ----------------
__global__ void k_final(const float* __restrict__ acc, float* __restrict__ out) {
    if (threadIdx.x == 0 && blockIdx.x == 0) {
        const float fB = 64.0f;
        float param_loss  = acc[0] / fB;
        float KLD         = -0.5f * acc[1] / fB * 10.0f;
        float recon_loss  = acc[2] / fB;
        float cmap_loss   = 3000.0f * acc[3] / (fB * acc[4]);
        float consistency = -5.0f * acc[6] / (acc[5] + 0.0001f);
        float penetr      = 100.0f * acc[7] / fB;
        out[0] = (recon_loss + KLD) + 0.1f * param_loss + 1000.0f * cmap_loss
               + 10.0f * consistency + 10.0f * penetr;
    }
}

extern "C" void kernel_launch(void* const* d_in, const int* in_sizes, int n_in,
                              void* d_out, int out_size, void* d_ws, size_t ws_size,
                              hipStream_t stream) {
    (void)in_sizes; (void)n_in; (void)out_size; (void)ws_size;
    const float* obj     = (const float*)d_in[0];
    const float* recon   = (const float*)d_in[1];
    const float* gt      = (const float*)d_in[2];
    const float* mean    = (const float*)d_in[3];
    const float* log_var = (const float*)d_in[4];
    const float* rp      = (const float*)d_in[5];
    const float* xp      = (const float*)d_in[6];
    const int*   faces   = (const int*)d_in[7];
    float* acc = (float*)d_ws;
    float* out = (float*)d_out;

    k_small  <<<1,        256, 0, stream>>>(mean, log_var, rp, xp, acc);
    k_chamfer<<<NB * 4,   256, 0, stream>>>(recon, gt, acc);
    k_main   <<<NB * CPB, 256, 0, stream>>>(obj, recon, gt, faces, acc);
    k_final  <<<1,        64,  0, stream>>>(acc, out);
}

// Round 2
// 320.384 us; speedup vs baseline: 1.0199x; 1.0199x over previous
//
#include <hip/hip_runtime.h>
#include <math.h>

// Problem constants (from reference setup_inputs)
#define NB     64      // batch
#define N1V    8192    // obj points per batch
#define NV     778     // recon / gt verts
#define NFACE  1538
#define NZ     64
#define NPAR   61
#define NPRIOR 204
#define PPT    8       // obj points per thread in main kernel
#define BIAS   0.0625f // makes rec-loop partial distance non-negative (2ab <= 0.06)

__device__ __constant__ int c_prior[NPRIOR] = {
  697,698,699,700,712,713,714,715,737,738,739,740,741,743,744,745,746,748,749,750,
  753,754,755,756,757,758,759,760,761,762,763,764,765,766,767,768,
  46,47,48,49,164,165,166,167,194,195,223,237,238,280,281,298,301,317,320,323,
  324,325,326,327,328,329,330,331,332,333,340,341,342,343,344,345,346,347,348,349,
  350,351,352,353,354,355,
  356,357,358,359,375,376,386,387,396,397,402,403,413,429,433,434,435,436,437,438,
  439,440,441,442,443,444,452,453,454,455,456,459,460,461,462,463,464,465,466,467,
  468,469,470,471,484,485,486,496,497,506,507,513,514,524,545,546,547,548,549,550,
  551,552,553,555,563,564,565,566,567,570,572,573,574,575,576,577,578,
  580,581,582,583,600,601,602,614,615,624,625,630,631,641,663,664,665,666,667,668,
  670,672,680,681,682,683,684,686,687,688,689,690,691,692,693,694,695,
  73,96,98,99,772,774,775,777
};

// Accumulator layout in d_ws (floats):
// 0: S_param  1: S_kld  2: S_recon(chamfer both dirs)  3: S_cmap  4: N_cmap
// 5: N_gt  6: N_consist  7: S_pen

// ---------------- Kernel 1: small reductions + accumulator init ----------------
__global__ __launch_bounds__(256) void k_small(const float* __restrict__ mean,
                                               const float* __restrict__ log_var,
                                               const float* __restrict__ rp,
                                               const float* __restrict__ xp,
                                               float* __restrict__ acc) {
    int tid = threadIdx.x;
    __shared__ float red[2];
    if (tid < 2) red[tid] = 0.0f;
    __syncthreads();
    float s_param = 0.0f, s_kld = 0.0f;
    for (int i = tid; i < NB * NPAR; i += 256) {
        float d = rp[i] - xp[i];
        s_param += d * d;
    }
    for (int i = tid; i < NB * NZ; i += 256) {
        float m = mean[i], lv = log_var[i];
        s_kld += 1.0f + lv - m * m - expf(lv);
    }
    atomicAdd(&red[0], s_param);
    atomicAdd(&red[1], s_kld);
    __syncthreads();
    if (tid < 2) acc[tid] = red[tid];
    if (tid >= 2 && tid < 8) acc[tid] = 0.0f;   // zero the running accumulators
}

// ---------------- Kernel 2: chamfer(recon, gt) both directions ----------------
// grid = NB * 2 blocks. block -> (batch, direction). Targets staged in LDS,
// sources read straight from global, 4 source points per thread.
__global__ __launch_bounds__(256) void k_chamfer(const float* __restrict__ recon,
                                                 const float* __restrict__ gt,
                                                 float* __restrict__ acc) {
    int b   = blockIdx.x >> 1;
    int dir = blockIdx.x & 1;          // 0: rec->gt, 1: gt->rec
    int tid = threadIdx.x;
    __shared__ float4 s_t[NV];
    __shared__ float red;
    if (tid == 0) red = 0.0f;
    const float* sb = (dir ? gt : recon) + (size_t)b * NV * 3;
    const float* tb = (dir ? recon : gt) + (size_t)b * NV * 3;
    for (int j = tid; j < NV; j += 256) {
        float x = tb[3*j], y = tb[3*j+1], z = tb[3*j+2];
        s_t[j] = make_float4(x, y, z, x*x + y*y + z*z);
    }
    __syncthreads();

    const int CPT = 4;                 // 256*4 = 1024 >= 778
    float nax[CPT], nay[CPT], naz[CPT], a2[CPT], m[CPT];
    bool valid[CPT];
#pragma unroll
    for (int k = 0; k < CPT; ++k) {
        int p = tid + 256 * k;
        valid[k] = (p < NV);
        int pp = valid[k] ? p : 0;
        float x = sb[3*pp], y = sb[3*pp+1], z = sb[3*pp+2];
        nax[k] = -2.0f * x; nay[k] = -2.0f * y; naz[k] = -2.0f * z;
        a2[k] = x*x + y*y + z*z;
        m[k] = 3.4e38f;
    }
    for (int j = 0; j < NV; j += 2) {
        float4 t0 = s_t[j], t1 = s_t[j+1];
#pragma unroll
        for (int k = 0; k < CPT; ++k) {
            float d0 = fmaf(nax[k], t0.x, fmaf(nay[k], t0.y, fmaf(naz[k], t0.z, t0.w)));
            float d1 = fmaf(nax[k], t1.x, fmaf(nay[k], t1.y, fmaf(naz[k], t1.z, t1.w)));
            m[k] = fminf(fminf(m[k], d0), d1);   // -> v_min3_f32
        }
    }
    float local = 0.0f;
#pragma unroll
    for (int k = 0; k < CPT; ++k)
        if (valid[k]) local += fmaxf(a2[k] + m[k], 0.0f);
    atomicAdd(&red, local);
    __syncthreads();
    if (tid == 0) atomicAdd(&acc[2], red);
}

// ---------------- Kernel 3: main per-obj-point KNNs + flags ----------------
// grid = NB * 4 blocks; 256 threads; 8 points/thread (2048 points/block).
__global__ __launch_bounds__(256) void k_main(const float* __restrict__ obj,
                                              const float* __restrict__ recon,
                                              const float* __restrict__ gt,
                                              const int* __restrict__ faces,
                                              float* __restrict__ acc) {
    int b = blockIdx.x >> 2;     // batch
    int chunk = blockIdx.x & 3;  // 2048-point chunk
    int tid = threadIdx.x;

    __shared__ float4 s_gt[NV];    // w = |t|^2            (unbiased)
    __shared__ float4 s_rec[NV];   // w = |t|^2 + BIAS     (biased for uint-min)
    __shared__ float4 s_pri[NPRIOR];
    __shared__ float s_vnx[NV], s_vny[NV], s_vnz[NV];
    __shared__ float s_red[5];

    const float* rb = recon + (size_t)b * NV * 3;
    const float* gb = gt    + (size_t)b * NV * 3;
    for (int j = tid; j < NV; j += 256) {
        float x = rb[3*j], y = rb[3*j+1], z = rb[3*j+2];
        s_rec[j] = make_float4(x, y, z, x*x + y*y + z*z + BIAS);
        x = gb[3*j]; y = gb[3*j+1]; z = gb[3*j+2];
        s_gt[j] = make_float4(x, y, z, x*x + y*y + z*z);
        s_vnx[j] = 0.0f; s_vny[j] = 0.0f; s_vnz[j] = 0.0f;
    }
    if (tid < 5) s_red[tid] = 0.0f;
    __syncthreads();

    // face normals accumulated into vertex normals (LDS atomics)
    for (int f = tid; f < NFACE; f += 256) {
        int i0 = faces[3*f], i1 = faces[3*f+1], i2 = faces[3*f+2];
        float4 p0 = s_rec[i0], p1 = s_rec[i1], p2 = s_rec[i2];
        float e1x = p1.x - p0.x, e1y = p1.y - p0.y, e1z = p1.z - p0.z;
        float e2x = p2.x - p0.x, e2y = p2.y - p0.y, e2z = p2.z - p0.z;
        float fx = e1y * e2z - e1z * e2y;
        float fy = e1z * e2x - e1x * e2z;
        float fz = e1x * e2y - e1y * e2x;
        atomicAdd(&s_vnx[i0], fx); atomicAdd(&s_vny[i0], fy); atomicAdd(&s_vnz[i0], fz);
        atomicAdd(&s_vnx[i1], fx); atomicAdd(&s_vny[i1], fy); atomicAdd(&s_vnz[i1], fz);
        atomicAdd(&s_vnx[i2], fx); atomicAdd(&s_vny[i2], fy); atomicAdd(&s_vnz[i2], fz);
    }
    __syncthreads();
    // normalize normals; build prior subset (biased w inherited from s_rec)
    for (int j = tid; j < NV; j += 256) {
        float x = s_vnx[j], y = s_vny[j], z = s_vnz[j];
        float inv = 1.0f / (sqrtf(x*x + y*y + z*z) + 1e-12f);
        s_vnx[j] = x * inv; s_vny[j] = y * inv; s_vnz[j] = z * inv;
    }
    for (int k = tid; k < NPRIOR; k += 256) s_pri[k] = s_rec[c_prior[k]];
    __syncthreads();

    // each thread: PPT consecutive obj points (8 pts = 24 floats = 6 float4)
    const float* ob = obj + ((size_t)b * N1V + (size_t)chunk * 2048) * 3;
    const float4* ob4 = (const float4*)(ob + (size_t)tid * PPT * 3);
    float4 q0 = ob4[0], q1 = ob4[1], q2 = ob4[2], q3 = ob4[3], q4 = ob4[4], q5 = ob4[5];
    float px[PPT], py[PPT], pz[PPT];
    px[0]=q0.x; py[0]=q0.y; pz[0]=q0.z;
    px[1]=q0.w; py[1]=q1.x; pz[1]=q1.y;
    px[2]=q1.z; py[2]=q1.w; pz[2]=q2.x;
    px[3]=q2.y; py[3]=q2.z; pz[3]=q2.w;
    px[4]=q3.x; py[4]=q3.y; pz[4]=q3.z;
    px[5]=q3.w; py[5]=q4.x; pz[5]=q4.y;
    px[6]=q4.z; py[6]=q4.w; pz[6]=q5.x;
    px[7]=q5.y; py[7]=q5.z; pz[7]=q5.w;

    float nax[PPT], nay[PPT], naz[PPT], a2[PPT];
    float mgt[PPT], mpri[PPT];
    unsigned int mu[PPT];
#pragma unroll
    for (int i = 0; i < PPT; ++i) {
        nax[i] = -2.0f * px[i]; nay[i] = -2.0f * py[i]; naz[i] = -2.0f * pz[i];
        a2[i] = px[i]*px[i] + py[i]*py[i] + pz[i]*pz[i];
        mgt[i] = 3.4e38f; mpri[i] = 3.4e38f; mu[i] = 0xFFFFFFFFu;
    }

    // --- gt loop: plain min, unroll 2 for v_min3 ---
    for (int j = 0; j < NV; j += 2) {
        float4 t0 = s_gt[j], t1 = s_gt[j+1];
#pragma unroll
        for (int i = 0; i < PPT; ++i) {
            float d0 = fmaf(nax[i], t0.x, fmaf(nay[i], t0.y, fmaf(naz[i], t0.z, t0.w)));
            float d1 = fmaf(nax[i], t1.x, fmaf(nay[i], t1.y, fmaf(naz[i], t1.z, t1.w)));
            mgt[i] = fminf(fminf(mgt[i], d0), d1);
        }
    }
    // --- rec loop: packed (distance | index) uint-min argmin ---
    // biased d >= 0, so float bits are monotone as uint; low 10 bits carry j.
    for (int j = 0; j < NV; ++j) {
        float4 t = s_rec[j];
        unsigned int uj = (unsigned int)j;
#pragma unroll
        for (int i = 0; i < PPT; ++i) {
            float d = fmaf(nax[i], t.x, fmaf(nay[i], t.y, fmaf(naz[i], t.z, t.w)));
            unsigned int u = (__float_as_uint(d) & 0xFFFFFC00u) | uj;
            mu[i] = min(mu[i], u);
        }
    }
    // --- prior loop: plain min on biased values, unroll 2 ---
    for (int j = 0; j < NPRIOR; j += 2) {
        float4 t0 = s_pri[j], t1 = s_pri[j+1];
#pragma unroll
        for (int i = 0; i < PPT; ++i) {
            float d0 = fmaf(nax[i], t0.x, fmaf(nay[i], t0.y, fmaf(naz[i], t0.z, t0.w)));
            float d1 = fmaf(nax[i], t1.x, fmaf(nay[i], t1.y, fmaf(naz[i], t1.z, t1.w)));
            mpri[i] = fminf(fminf(mpri[i], d0), d1);
        }
    }

    float lS_cmap = 0.0f, lN_cmap = 0.0f, lN_gt = 0.0f, lN_cons = 0.0f, lS_pen = 0.0f;
#pragma unroll
    for (int i = 0; i < PPT; ++i) {
        float dgt  = fmaxf(a2[i] + mgt[i],          0.0f);
        float dpri = fmaxf(a2[i] + (mpri[i] - BIAS), 0.0f);
        int j = (int)(mu[i] & 0x3FFu);
        float4 t = s_rec[j];
        // exact d_rec recompute for the chosen neighbor
        float dot = fmaf(nax[i], t.x, fmaf(nay[i], t.y, fmaf(naz[i], t.z, t.w - BIAS)));
        float drec = fmaxf(a2[i] + dot, 0.0f);
        bool cm = drec < 1e-4f;                 // d_rec < 0.01^2
        bool rc = sqrtf(drec) < 0.005f;         // recon_cmap
        bool gc = sqrtf(dgt)  < 0.005f;         // gt_cmap
        if (cm) { lS_cmap += dpri; lN_cmap += 1.0f; }
        if (gc) { lN_gt += 1.0f; if (rc) lN_cons += 1.0f; }
        float axv = -0.5f * nax[i], ayv = -0.5f * nay[i], azv = -0.5f * naz[i];
        float ddot = (t.x - axv) * s_vnx[j]
                   + (t.y - ayv) * s_vny[j]
                   + (t.z - azv) * s_vnz[j];
        if (ddot > 0.0f) lS_pen += drec;
    }
    atomicAdd(&s_red[0], lS_cmap);
    atomicAdd(&s_red[1], lN_cmap);
    atomicAdd(&s_red[2], lN_gt);
    atomicAdd(&s_red[3], lN_cons);
    atomicAdd(&s_red[4], lS_pen);
    __syncthreads();
    if (tid < 5) atomicAdd(&acc[3 + tid], s_red[tid]);
}

// ---------------- Kernel 4: finalize ----------------
__global__ void k_final(const float* __restrict__ acc, float* __restrict__ out) {
    if (threadIdx.x == 0 && blockIdx.x == 0) {
        const float fB = 64.0f;
        float param_loss  = acc[0] / fB;
        float KLD         = -0.5f * acc[1] / fB * 10.0f;
        float recon_loss  = acc[2] / fB;
        float cmap_loss   = 3000.0f * acc[3] / (fB * acc[4]);
        float consistency = -5.0f * acc[6] / (acc[5] + 0.0001f);
        float penetr      = 100.0f * acc[7] / fB;
        out[0] = (recon_loss + KLD) + 0.1f * param_loss + 1000.0f * cmap_loss
               + 10.0f * consistency + 10.0f * penetr;
    }
}

extern "C" void kernel_launch(void* const* d_in, const int* in_sizes, int n_in,
                              void* d_out, int out_size, void* d_ws, size_t ws_size,
                              hipStream_t stream) {
    (void)in_sizes; (void)n_in; (void)out_size; (void)ws_size;
    const float* obj     = (const float*)d_in[0];
    const float* recon   = (const float*)d_in[1];
    const float* gt      = (const float*)d_in[2];
    const float* mean    = (const float*)d_in[3];
    const float* log_var = (const float*)d_in[4];
    const float* rp      = (const float*)d_in[5];
    const float* xp      = (const float*)d_in[6];
    const int*   faces   = (const int*)d_in[7];
    float* acc = (float*)d_ws;
    float* out = (float*)d_out;

    k_small  <<<1,      256, 0, stream>>>(mean, log_var, rp, xp, acc);
    k_chamfer<<<NB * 2, 256, 0, stream>>>(recon, gt, acc);
    k_main   <<<NB * 4, 256, 0, stream>>>(obj, recon, gt, faces, acc);
    k_final  <<<1,      64,  0, stream>>>(acc, out);
}

// Round 3
// 244.499 us; speedup vs baseline: 1.3365x; 1.3104x over previous
//
#include <hip/hip_runtime.h>
#include <math.h>

// Problem constants (from reference setup_inputs)
#define NB     64      // batch
#define N1V    8192    // obj points per batch
#define NV     778     // recon / gt verts
#define NFACE  1538
#define NZ     64
#define NPAR   61
#define NPRIOR 204
#define PPT    4       // obj points per thread in main role
#define MAIN_BLOCKS (NB * 8)                 // 512: 1024 obj pts per block
#define CHAM_BLOCKS (NB * 4)                 // 256: (batch, dir, half)
#define TOT_BLOCKS  (MAIN_BLOCKS + CHAM_BLOCKS)
#define HALF_SRC 389                          // 778/2 sources per chamfer block
#define BIAS   0.0625f // makes rec-loop partial distance non-negative (2ab <= 0.06)

__device__ __constant__ int c_prior[NPRIOR] = {
  697,698,699,700,712,713,714,715,737,738,739,740,741,743,744,745,746,748,749,750,
  753,754,755,756,757,758,759,760,761,762,763,764,765,766,767,768,
  46,47,48,49,164,165,166,167,194,195,223,237,238,280,281,298,301,317,320,323,
  324,325,326,327,328,329,330,331,332,333,340,341,342,343,344,345,346,347,348,349,
  350,351,352,353,354,355,
  356,357,358,359,375,376,386,387,396,397,402,403,413,429,433,434,435,436,437,438,
  439,440,441,442,443,444,452,453,454,455,456,459,460,461,462,463,464,465,466,467,
  468,469,470,471,484,485,486,496,497,506,507,513,514,524,545,546,547,548,549,550,
  551,552,553,555,563,564,565,566,567,570,572,573,574,575,576,577,578,
  580,581,582,583,600,601,602,614,615,624,625,630,631,641,663,664,665,666,667,668,
  670,672,680,681,682,683,684,686,687,688,689,690,691,692,693,694,695,
  73,96,98,99,772,774,775,777
};

// ws layout: float[TOT_BLOCKS][8], each block writes ALL 8 of its row's slots
// (unused = 0) so no init / no atomics / no ordering needed.
// col 2: chamfer partial   3: S_cmap   4: N_cmap   5: N_gt   6: N_cons   7: S_pen

// ---------------- Fused kernel: main KNNs (blocks 0..511) + chamfer (512..767) --
__global__ __launch_bounds__(256) void k_fused(const float* __restrict__ obj,
                                               const float* __restrict__ recon,
                                               const float* __restrict__ gt,
                                               const int* __restrict__ faces,
                                               float* __restrict__ ws) {
    __shared__ float4 s_gt[NV];    // main: gt targets | chamfer: target set
    __shared__ float4 s_rec[NV];   // main only: w = |t|^2 + BIAS
    __shared__ float4 s_pri[NPRIOR];
    __shared__ float s_vnx[NV], s_vny[NV], s_vnz[NV];
    __shared__ float s_red[5];

    int tid = threadIdx.x;

    if (blockIdx.x >= MAIN_BLOCKS) {
        // ================== CHAMFER ROLE ==================
        int c    = blockIdx.x - MAIN_BLOCKS;
        int b    = c >> 2;
        int dir  = (c >> 1) & 1;   // 0: rec->gt, 1: gt->rec
        int half = c & 1;
        if (tid == 0) s_red[0] = 0.0f;
        const float* sb = (dir ? gt : recon) + (size_t)b * NV * 3;
        const float* tb = (dir ? recon : gt) + (size_t)b * NV * 3;
        for (int j = tid; j < NV; j += 256) {
            float x = tb[3*j], y = tb[3*j+1], z = tb[3*j+2];
            s_gt[j] = make_float4(x, y, z, x*x + y*y + z*z);
        }
        __syncthreads();

        const int CPT = 2;               // 256*2 = 512 >= 389 sources
        float nax[CPT], nay[CPT], naz[CPT], a2[CPT], m[CPT];
        bool valid[CPT];
#pragma unroll
        for (int k = 0; k < CPT; ++k) {
            int p = half * HALF_SRC + tid + 256 * k;
            valid[k] = (p < (half + 1) * HALF_SRC);
            int pp = valid[k] ? p : 0;
            float x = sb[3*pp], y = sb[3*pp+1], z = sb[3*pp+2];
            nax[k] = -2.0f * x; nay[k] = -2.0f * y; naz[k] = -2.0f * z;
            a2[k] = x*x + y*y + z*z;
            m[k] = 3.4e38f;
        }
        float4 t0 = s_gt[0], t1 = s_gt[1];
        for (int j = 0; j < NV - 2; j += 2) {
            float4 n0 = s_gt[j+2], n1 = s_gt[j+3];
#pragma unroll
            for (int k = 0; k < CPT; ++k) {
                float d0 = fmaf(nax[k], t0.x, fmaf(nay[k], t0.y, fmaf(naz[k], t0.z, t0.w)));
                float d1 = fmaf(nax[k], t1.x, fmaf(nay[k], t1.y, fmaf(naz[k], t1.z, t1.w)));
                m[k] = fminf(fminf(m[k], d0), d1);
            }
            t0 = n0; t1 = n1;
        }
#pragma unroll
        for (int k = 0; k < CPT; ++k) {
            float d0 = fmaf(nax[k], t0.x, fmaf(nay[k], t0.y, fmaf(naz[k], t0.z, t0.w)));
            float d1 = fmaf(nax[k], t1.x, fmaf(nay[k], t1.y, fmaf(naz[k], t1.z, t1.w)));
            m[k] = fminf(fminf(m[k], d0), d1);
        }
        float local = 0.0f;
#pragma unroll
        for (int k = 0; k < CPT; ++k)
            if (valid[k]) local += fmaxf(a2[k] + m[k], 0.0f);
        atomicAdd(&s_red[0], local);
        __syncthreads();
        if (tid < 8) {
            float v = (tid == 2) ? s_red[0] : 0.0f;
            ws[(size_t)blockIdx.x * 8 + tid] = v;
        }
        return;
    }

    // ================== MAIN ROLE ==================
    int b = blockIdx.x >> 3;     // batch
    int chunk = blockIdx.x & 7;  // 1024-point chunk

    const float* rb = recon + (size_t)b * NV * 3;
    const float* gb = gt    + (size_t)b * NV * 3;
    for (int j = tid; j < NV; j += 256) {
        float x = rb[3*j], y = rb[3*j+1], z = rb[3*j+2];
        s_rec[j] = make_float4(x, y, z, x*x + y*y + z*z + BIAS);
        x = gb[3*j]; y = gb[3*j+1]; z = gb[3*j+2];
        s_gt[j] = make_float4(x, y, z, x*x + y*y + z*z);
        s_vnx[j] = 0.0f; s_vny[j] = 0.0f; s_vnz[j] = 0.0f;
    }
    if (tid < 5) s_red[tid] = 0.0f;
    __syncthreads();

    // face normals accumulated into vertex normals (LDS atomics)
    for (int f = tid; f < NFACE; f += 256) {
        int i0 = faces[3*f], i1 = faces[3*f+1], i2 = faces[3*f+2];
        float4 p0 = s_rec[i0], p1 = s_rec[i1], p2 = s_rec[i2];
        float e1x = p1.x - p0.x, e1y = p1.y - p0.y, e1z = p1.z - p0.z;
        float e2x = p2.x - p0.x, e2y = p2.y - p0.y, e2z = p2.z - p0.z;
        float fx = e1y * e2z - e1z * e2y;
        float fy = e1z * e2x - e1x * e2z;
        float fz = e1x * e2y - e1y * e2x;
        atomicAdd(&s_vnx[i0], fx); atomicAdd(&s_vny[i0], fy); atomicAdd(&s_vnz[i0], fz);
        atomicAdd(&s_vnx[i1], fx); atomicAdd(&s_vny[i1], fy); atomicAdd(&s_vnz[i1], fz);
        atomicAdd(&s_vnx[i2], fx); atomicAdd(&s_vny[i2], fy); atomicAdd(&s_vnz[i2], fz);
    }
    __syncthreads();
    // normalize normals; build prior subset (biased w inherited from s_rec)
    for (int j = tid; j < NV; j += 256) {
        float x = s_vnx[j], y = s_vny[j], z = s_vnz[j];
        float inv = 1.0f / (sqrtf(x*x + y*y + z*z) + 1e-12f);
        s_vnx[j] = x * inv; s_vny[j] = y * inv; s_vnz[j] = z * inv;
    }
    for (int k = tid; k < NPRIOR; k += 256) s_pri[k] = s_rec[c_prior[k]];
    __syncthreads();

    // each thread: PPT=4 consecutive obj points (12 floats = 3 float4)
    const float* ob = obj + ((size_t)b * N1V + (size_t)chunk * 1024) * 3;
    const float4* ob4 = (const float4*)(ob + (size_t)tid * PPT * 3);
    float4 q0 = ob4[0], q1 = ob4[1], q2 = ob4[2];
    float px[PPT], py[PPT], pz[PPT];
    px[0]=q0.x; py[0]=q0.y; pz[0]=q0.z;
    px[1]=q0.w; py[1]=q1.x; pz[1]=q1.y;
    px[2]=q1.z; py[2]=q1.w; pz[2]=q2.x;
    px[3]=q2.y; py[3]=q2.z; pz[3]=q2.w;

    float nax[PPT], nay[PPT], naz[PPT], a2[PPT];
    float mgt[PPT], mpri[PPT];
    unsigned int mu[PPT];
#pragma unroll
    for (int i = 0; i < PPT; ++i) {
        nax[i] = -2.0f * px[i]; nay[i] = -2.0f * py[i]; naz[i] = -2.0f * pz[i];
        a2[i] = px[i]*px[i] + py[i]*py[i] + pz[i]*pz[i];
        mgt[i] = 3.4e38f; mpri[i] = 3.4e38f; mu[i] = 0xFFFFFFFFu;
    }

    // --- gt loop: register-pipelined, min3 ---
    {
        float4 t0 = s_gt[0], t1 = s_gt[1];
        for (int j = 0; j < NV - 2; j += 2) {
            float4 n0 = s_gt[j+2], n1 = s_gt[j+3];
#pragma unroll
            for (int i = 0; i < PPT; ++i) {
                float d0 = fmaf(nax[i], t0.x, fmaf(nay[i], t0.y, fmaf(naz[i], t0.z, t0.w)));
                float d1 = fmaf(nax[i], t1.x, fmaf(nay[i], t1.y, fmaf(naz[i], t1.z, t1.w)));
                mgt[i] = fminf(fminf(mgt[i], d0), d1);
            }
            t0 = n0; t1 = n1;
        }
#pragma unroll
        for (int i = 0; i < PPT; ++i) {
            float d0 = fmaf(nax[i], t0.x, fmaf(nay[i], t0.y, fmaf(naz[i], t0.z, t0.w)));
            float d1 = fmaf(nax[i], t1.x, fmaf(nay[i], t1.y, fmaf(naz[i], t1.z, t1.w)));
            mgt[i] = fminf(fminf(mgt[i], d0), d1);
        }
    }
    // --- rec loop: packed (distance | index) uint-min argmin, pipelined ---
    // biased d >= 0, so float bits are monotone as uint; low 10 bits carry j.
    {
        float4 t0 = s_rec[0], t1 = s_rec[1];
        for (int j = 0; j < NV - 2; j += 2) {
            float4 n0 = s_rec[j+2], n1 = s_rec[j+3];
            unsigned int ua = (unsigned int)j, ub = (unsigned int)(j + 1);
#pragma unroll
            for (int i = 0; i < PPT; ++i) {
                float d0 = fmaf(nax[i], t0.x, fmaf(nay[i], t0.y, fmaf(naz[i], t0.z, t0.w)));
                float d1 = fmaf(nax[i], t1.x, fmaf(nay[i], t1.y, fmaf(naz[i], t1.z, t1.w)));
                unsigned int u0 = (__float_as_uint(d0) & 0xFFFFFC00u) | ua;
                unsigned int u1 = (__float_as_uint(d1) & 0xFFFFFC00u) | ub;
                mu[i] = min(mu[i], min(u0, u1));     // -> v_min3_u32
            }
            t0 = n0; t1 = n1;
        }
#pragma unroll
        for (int i = 0; i < PPT; ++i) {
            float d0 = fmaf(nax[i], t0.x, fmaf(nay[i], t0.y, fmaf(naz[i], t0.z, t0.w)));
            float d1 = fmaf(nax[i], t1.x, fmaf(nay[i], t1.y, fmaf(naz[i], t1.z, t1.w)));
            unsigned int u0 = (__float_as_uint(d0) & 0xFFFFFC00u) | 776u;
            unsigned int u1 = (__float_as_uint(d1) & 0xFFFFFC00u) | 777u;
            mu[i] = min(mu[i], min(u0, u1));
        }
    }
    // --- prior loop: biased values, pipelined ---
    {
        float4 t0 = s_pri[0], t1 = s_pri[1];
        for (int j = 0; j < NPRIOR - 2; j += 2) {
            float4 n0 = s_pri[j+2], n1 = s_pri[j+3];
#pragma unroll
            for (int i = 0; i < PPT; ++i) {
                float d0 = fmaf(nax[i], t0.x, fmaf(nay[i], t0.y, fmaf(naz[i], t0.z, t0.w)));
                float d1 = fmaf(nax[i], t1.x, fmaf(nay[i], t1.y, fmaf(naz[i], t1.z, t1.w)));
                mpri[i] = fminf(fminf(mpri[i], d0), d1);
            }
            t0 = n0; t1 = n1;
        }
#pragma unroll
        for (int i = 0; i < PPT; ++i) {
            float d0 = fmaf(nax[i], t0.x, fmaf(nay[i], t0.y, fmaf(naz[i], t0.z, t0.w)));
            float d1 = fmaf(nax[i], t1.x, fmaf(nay[i], t1.y, fmaf(naz[i], t1.z, t1.w)));
            mpri[i] = fminf(fminf(mpri[i], d0), d1);
        }
    }

    float lS_cmap = 0.0f, lN_cmap = 0.0f, lN_gt = 0.0f, lN_cons = 0.0f, lS_pen = 0.0f;
#pragma unroll
    for (int i = 0; i < PPT; ++i) {
        float dgt  = fmaxf(a2[i] + mgt[i],           0.0f);
        float dpri = fmaxf(a2[i] + (mpri[i] - BIAS), 0.0f);
        int j = (int)(mu[i] & 0x3FFu);
        float4 t = s_rec[j];
        // exact d_rec recompute for the chosen neighbor
        float dot = fmaf(nax[i], t.x, fmaf(nay[i], t.y, fmaf(naz[i], t.z, t.w - BIAS)));
        float drec = fmaxf(a2[i] + dot, 0.0f);
        bool cm = drec < 1e-4f;                 // d_rec < 0.01^2
        bool rc = sqrtf(drec) < 0.005f;         // recon_cmap
        bool gc = sqrtf(dgt)  < 0.005f;         // gt_cmap
        if (cm) { lS_cmap += dpri; lN_cmap += 1.0f; }
        if (gc) { lN_gt += 1.0f; if (rc) lN_cons += 1.0f; }
        float axv = -0.5f * nax[i], ayv = -0.5f * nay[i], azv = -0.5f * naz[i];
        float ddot = (t.x - axv) * s_vnx[j]
                   + (t.y - ayv) * s_vny[j]
                   + (t.z - azv) * s_vnz[j];
        if (ddot > 0.0f) lS_pen += drec;
    }
    atomicAdd(&s_red[0], lS_cmap);
    atomicAdd(&s_red[1], lN_cmap);
    atomicAdd(&s_red[2], lN_gt);
    atomicAdd(&s_red[3], lN_cons);
    atomicAdd(&s_red[4], lS_pen);
    __syncthreads();
    if (tid < 8) {
        float v = (tid >= 3) ? s_red[tid - 3] : 0.0f;
        ws[(size_t)blockIdx.x * 8 + tid] = v;
    }
}

// ---------------- Finalize: param/KLD reductions + ws row-sum + loss ----------
__global__ __launch_bounds__(256) void k_final(const float* __restrict__ ws,
                                               const float* __restrict__ mean,
                                               const float* __restrict__ log_var,
                                               const float* __restrict__ rp,
                                               const float* __restrict__ xp,
                                               float* __restrict__ out) {
    int tid = threadIdx.x;
    __shared__ float red[8];
    if (tid < 8) red[tid] = 0.0f;
    __syncthreads();
    float l2=0, l3=0, l4=0, l5=0, l6=0, l7=0;
    for (int r = tid; r < TOT_BLOCKS; r += 256) {
        const float* row = ws + (size_t)r * 8;
        l2 += row[2]; l3 += row[3]; l4 += row[4];
        l5 += row[5]; l6 += row[6]; l7 += row[7];
    }
    float s_param = 0.0f, s_kld = 0.0f;
    for (int i = tid; i < NB * NPAR; i += 256) {
        float d = rp[i] - xp[i];
        s_param += d * d;
    }
    for (int i = tid; i < NB * NZ; i += 256) {
        float m = mean[i], lv = log_var[i];
        s_kld += 1.0f + lv - m * m - expf(lv);
    }
    atomicAdd(&red[0], s_param);
    atomicAdd(&red[1], s_kld);
    atomicAdd(&red[2], l2);
    atomicAdd(&red[3], l3);
    atomicAdd(&red[4], l4);
    atomicAdd(&red[5], l5);
    atomicAdd(&red[6], l6);
    atomicAdd(&red[7], l7);
    __syncthreads();
    if (tid == 0) {
        const float fB = 64.0f;
        float param_loss  = red[0] / fB;
        float KLD         = -0.5f * red[1] / fB * 10.0f;
        float recon_loss  = red[2] / fB;
        float cmap_loss   = 3000.0f * red[3] / (fB * red[4]);
        float consistency = -5.0f * red[6] / (red[5] + 0.0001f);
        float penetr      = 100.0f * red[7] / fB;
        out[0] = (recon_loss + KLD) + 0.1f * param_loss + 1000.0f * cmap_loss
               + 10.0f * consistency + 10.0f * penetr;
    }
}

extern "C" void kernel_launch(void* const* d_in, const int* in_sizes, int n_in,
                              void* d_out, int out_size, void* d_ws, size_t ws_size,
                              hipStream_t stream) {
    (void)in_sizes; (void)n_in; (void)out_size; (void)ws_size;
    const float* obj     = (const float*)d_in[0];
    const float* recon   = (const float*)d_in[1];
    const float* gt      = (const float*)d_in[2];
    const float* mean    = (const float*)d_in[3];
    const float* log_var = (const float*)d_in[4];
    const float* rp      = (const float*)d_in[5];
    const float* xp      = (const float*)d_in[6];
    const int*   faces   = (const int*)d_in[7];
    float* ws  = (float*)d_ws;
    float* out = (float*)d_out;

    k_fused<<<TOT_BLOCKS, 256, 0, stream>>>(obj, recon, gt, faces, ws);
    k_final<<<1,          256, 0, stream>>>(ws, mean, log_var, rp, xp, out);
}